// Round 3
// baseline (586.834 us; speedup 1.0000x reference)
//
#include <hip/hip_runtime.h>
#include <hip/hip_bf16.h>
#include <cstdint>

#define B_    4
#define S_    2048
#define D_    1024
#define SCALE 0.03125f     // 1/sqrt(1024)
#define NEG_BIG -1e9f

typedef __attribute__((ext_vector_type(8))) short short8;   // 8 bf16 (4 VGPRs)
typedef __attribute__((ext_vector_type(4))) float f32x4;    // MFMA C/D frag

__device__ __forceinline__ ushort f2bf(float f) {
  uint32_t u = __float_as_uint(f);
  u += 0x7fffu + ((u >> 16) & 1u);   // round-to-nearest-even
  return (ushort)(u >> 16);
}

// ---------------- kernel 0a: K fp32 -> bf16 ----------------
__global__ void convert_k(const float* __restrict__ K, ushort* __restrict__ Kb) {
  size_t i = ((size_t)blockIdx.x * 256 + threadIdx.x) * 8;
  float4 a = *(const float4*)(K + i);
  float4 c = *(const float4*)(K + i + 4);
  uint4 w;
  w.x = (uint)f2bf(a.x) | ((uint)f2bf(a.y) << 16);
  w.y = (uint)f2bf(a.z) | ((uint)f2bf(a.w) << 16);
  w.z = (uint)f2bf(c.x) | ((uint)f2bf(c.y) << 16);
  w.w = (uint)f2bf(c.z) | ((uint)f2bf(c.w) << 16);
  *(uint4*)(Kb + i) = w;
}

// ---------------- kernel 0b: V fp32 -> bf16 transposed Vt[b][d][s] ----------------
__global__ void transpose_v(const float* __restrict__ V, ushort* __restrict__ Vt) {
  __shared__ ushort tile[64][68];
  int tx = threadIdx.x & 15, ty = threadIdx.x >> 4;
  int s0 = blockIdx.x * 64, d0 = blockIdx.y * 64, b = blockIdx.z;
  const float* src = V + ((size_t)b * S_ + s0) * D_ + d0;
  for (int i = 0; i < 4; ++i) {
    int row = ty + i * 16;
    float4 a = *(const float4*)(src + (size_t)row * D_ + tx * 4);
    ushort4 w;
    w.x = f2bf(a.x); w.y = f2bf(a.y); w.z = f2bf(a.z); w.w = f2bf(a.w);
    *(ushort4*)&tile[row][tx * 4] = w;
  }
  __syncthreads();
  ushort* dst = Vt + ((size_t)b * D_ + d0) * S_ + s0;
  for (int i = 0; i < 4; ++i) {
    int drow = ty + i * 16;
    ushort4 w;
    w.x = tile[tx * 4 + 0][drow];
    w.y = tile[tx * 4 + 1][drow];
    w.z = tile[tx * 4 + 2][drow];
    w.w = tile[tx * 4 + 3][drow];
    *(ushort4*)(dst + (size_t)drow * S_ + tx * 4) = w;
  }
}

// ---------------- kernel 1: fused flash attention ----------------
// grid 512 blocks (2 per CU -> 2 independent barrier domains), 512 threads.
// Block: one batch, 16 query rows. Wave w owns output D-slice [128w,128w+128).
// Single barrier per k-tile; sPart/sP/sAlpha double-buffered.
__launch_bounds__(512, 4)
__global__ void flash_attn(const float* __restrict__ Q, const ushort* __restrict__ Kb,
                           const ushort* __restrict__ Vt, const int* __restrict__ mask,
                           float* __restrict__ Out) {
  // batch b -> XCD pair {2b,2b+1}: blocks i and i+256 share a CU and a batch.
  int i = blockIdx.x;
  int b  = (i & 7) >> 1;
  int qt = ((i >> 3) << 1) | (i & 1);
  int q0 = qt * 16;

  int tid  = threadIdx.x;
  int lane = tid & 63;
  int wave = tid >> 6;      // 0..7
  int quad = lane >> 4;     // 0..3
  int l16  = lane & 15;

  __shared__ __align__(16) float  sPart[2][8][16][34];  // 34.8 KB
  __shared__ __align__(16) ushort sP[2][16][56];        // 3.5 KB
  __shared__ float sM[16], sL[16], sAlpha[2][16];

  if (tid < 16) { sM[tid] = -3.0e38f; sL[tid] = 0.f; }

  // ---- preload Q fragments: A[m = l16][k = quad*8 + j], 16 rows ----
  short8 qf[4];
  {
    const float* qbase = Q + (size_t)(b * S_ + q0 + l16) * D_ + wave * 128 + quad * 8;
    for (int kc = 0; kc < 4; ++kc) {
      const float* p = qbase + kc * 32;
      float4 a = *(const float4*)p;
      float4 c = *(const float4*)(p + 4);
      short8 v;
      v[0] = (short)f2bf(a.x); v[1] = (short)f2bf(a.y);
      v[2] = (short)f2bf(a.z); v[3] = (short)f2bf(a.w);
      v[4] = (short)f2bf(c.x); v[5] = (short)f2bf(c.y);
      v[6] = (short)f2bf(c.z); v[7] = (short)f2bf(c.w);
      qf[kc] = v;
    }
  }

  f32x4 o[8];
  for (int nt = 0; nt < 8; ++nt) o[nt] = (f32x4){0.f, 0.f, 0.f, 0.f};

  int srow = tid >> 5;          // stats: row 0..15 (32 threads each)
  int skp  = tid & 31;          // stats: 1 key per thread

  auto do_qk = [&](int t) {
    int k0 = t * 32, pb = t & 1;
    f32x4 sc[2];
    sc[0] = (f32x4){0.f, 0.f, 0.f, 0.f};
    sc[1] = (f32x4){0.f, 0.f, 0.f, 0.f};
    const ushort* kbase = Kb + (size_t)(b * S_ + k0 + l16) * D_ + wave * 128 + quad * 8;
    for (int kc = 0; kc < 4; ++kc) {
      short8 kb0 = *(const short8*)(kbase + kc * 32);
      short8 kb1 = *(const short8*)(kbase + (size_t)16 * D_ + kc * 32);
      sc[0] = __builtin_amdgcn_mfma_f32_16x16x32_bf16(qf[kc], kb0, sc[0], 0, 0, 0);
      sc[1] = __builtin_amdgcn_mfma_f32_16x16x32_bf16(qf[kc], kb1, sc[1], 0, 0, 0);
    }
    // C layout: col = lane&15, row = quad*4 + r
    for (int nt = 0; nt < 2; ++nt)
      for (int r = 0; r < 4; ++r)
        sPart[pb][wave][quad * 4 + r][nt * 16 + l16] = sc[nt][r];
  };

  auto do_stats = [&](int t) {
    int k0 = t * 32, pb = t & 1;
    float s = 0.f;
    for (int w = 0; w < 8; ++w) s += sPart[pb][w][srow][skp];
    int mk = mask[b * S_ + k0 + skp];
    float l = s * SCALE + (mk ? NEG_BIG : 0.f);
    float tmax = l;
    for (int off = 1; off <= 16; off <<= 1) tmax = fmaxf(tmax, __shfl_xor(tmax, off));
    float mold = sM[srow];
    float mnew = fmaxf(mold, tmax);
    float p = __expf(l - mnew);
    float ts = p;
    for (int off = 1; off <= 16; off <<= 1) ts += __shfl_xor(ts, off);
    float alpha = __expf(mold - mnew);
    if ((tid & 31) == 0) {
      sM[srow]         = mnew;
      sL[srow]         = sL[srow] * alpha + ts;
      sAlpha[pb][srow] = alpha;
    }
    sP[pb][srow][skp] = f2bf(p);
  };

  auto do_pv = [&](int t) {
    int k0 = t * 32, pb = t & 1;
    for (int r = 0; r < 4; ++r) {
      float a = sAlpha[pb][quad * 4 + r];
      for (int nt = 0; nt < 8; ++nt) o[nt][r] *= a;
    }
    short8 ap = *(const short8*)&sP[pb][l16][quad * 8];
    const ushort* vbase = Vt + ((size_t)b * D_ + wave * 128 + l16) * S_ + k0 + quad * 8;
    for (int nt = 0; nt < 8; ++nt) {
      short8 bv = *(const short8*)(vbase + (size_t)nt * 16 * S_);
      o[nt] = __builtin_amdgcn_mfma_f32_16x16x32_bf16(ap, bv, o[nt], 0, 0, 0);
    }
  };

  do_qk(0);
  __syncthreads();
  for (int t = 0; t < 64; ++t) {
    if (t < 63) do_qk(t + 1);
    if (t > 0)  do_pv(t - 1);
    do_stats(t);
    __syncthreads();
  }
  do_pv(63);

  // ---- epilogue ----
  float invl[4];
  for (int r = 0; r < 4; ++r) invl[r] = 1.0f / sL[quad * 4 + r];
  float* obase = Out + (size_t)(b * S_ + q0) * D_ + wave * 128 + l16;
  for (int r = 0; r < 4; ++r) {
    float* po = obase + (size_t)(quad * 4 + r) * D_;
    float s = invl[r];
    for (int nt = 0; nt < 8; ++nt) po[nt * 16] = o[nt][r] * s;
  }
}

extern "C" void kernel_launch(void* const* d_in, const int* in_sizes, int n_in,
                              void* d_out, int out_size, void* d_ws, size_t ws_size,
                              hipStream_t stream) {
  const float* Q   = (const float*)d_in[0];
  const float* K   = (const float*)d_in[1];
  const float* V   = (const float*)d_in[2];
  const int*  mask = (const int*)d_in[3];
  float* Out = (float*)d_out;

  ushort* Kb = (ushort*)d_ws;
  ushort* Vt = Kb + (size_t)B_ * S_ * D_;

  convert_k<<<4096, 256, 0, stream>>>(K, Kb);
  transpose_v<<<dim3(32, 16, 4), 256, 0, stream>>>(V, Vt);
  flash_attn<<<512, 512, 0, stream>>>(Q, Kb, Vt, mask, Out);
}

// Round 4
// 262.295 us; speedup vs baseline: 2.2373x; 2.2373x over previous
//
#include <hip/hip_runtime.h>
#include <hip/hip_bf16.h>
#include <cstdint>

#define B_    4
#define S_    2048
#define D_    1024
#define SCALE 0.03125f     // 1/sqrt(1024)
#define NEG_BIG -1e9f

typedef __attribute__((ext_vector_type(8))) short short8;   // 8 bf16 (4 VGPRs)
typedef __attribute__((ext_vector_type(4))) float f32x4;    // MFMA C/D frag

__device__ __forceinline__ ushort f2bf(float f) {
  uint32_t u = __float_as_uint(f);
  u += 0x7fffu + ((u >> 16) & 1u);   // round-to-nearest-even
  return (ushort)(u >> 16);
}

__device__ __forceinline__ void load16_to_lds(const void* g, void* l) {
  __builtin_amdgcn_global_load_lds(
      (const __attribute__((address_space(1))) uint32_t*)g,
      (__attribute__((address_space(3))) uint32_t*)l, 16, 0, 0);
}

// ---------------- fp32 -> bf16 bulk convert (Q and K) ----------------
__global__ void convert_bf16(const float* __restrict__ X, ushort* __restrict__ Xb) {
  size_t i = ((size_t)blockIdx.x * 256 + threadIdx.x) * 8;
  float4 a = *(const float4*)(X + i);
  float4 c = *(const float4*)(X + i + 4);
  uint4 w;
  w.x = (uint)f2bf(a.x) | ((uint)f2bf(a.y) << 16);
  w.y = (uint)f2bf(a.z) | ((uint)f2bf(a.w) << 16);
  w.z = (uint)f2bf(c.x) | ((uint)f2bf(c.y) << 16);
  w.w = (uint)f2bf(c.z) | ((uint)f2bf(c.w) << 16);
  *(uint4*)(Xb + i) = w;
}

// ---------------- V fp32 -> bf16 transposed Vt[b][d][s] ----------------
__global__ void transpose_v(const float* __restrict__ V, ushort* __restrict__ Vt) {
  __shared__ ushort tile[64][68];
  int tx = threadIdx.x & 15, ty = threadIdx.x >> 4;
  int s0 = blockIdx.x * 64, d0 = blockIdx.y * 64, b = blockIdx.z;
  const float* src = V + ((size_t)b * S_ + s0) * D_ + d0;
  for (int i = 0; i < 4; ++i) {
    int row = ty + i * 16;
    float4 a = *(const float4*)(src + (size_t)row * D_ + tx * 4);
    ushort4 w;
    w.x = f2bf(a.x); w.y = f2bf(a.y); w.z = f2bf(a.z); w.w = f2bf(a.w);
    *(ushort4*)&tile[row][tx * 4] = w;
  }
  __syncthreads();
  ushort* dst = Vt + ((size_t)b * D_ + d0) * S_ + s0;
  for (int i = 0; i < 4; ++i) {
    int drow = ty + i * 16;
    ushort4 w;
    w.x = tile[tx * 4 + 0][drow];
    w.y = tile[tx * 4 + 1][drow];
    w.z = tile[tx * 4 + 2][drow];
    w.w = tile[tx * 4 + 3][drow];
    *(ushort4*)(dst + (size_t)drow * S_ + tx * 4) = w;
  }
}

// ---------------- m97-style GEMM: C = A * Bt^T (both row-major over K-dim) ----
// 128x128 tile, 256 threads (4 waves, each 64x64 = 4x4 MFMA tiles), BK=32,
// global_load_lds width-16 staging, 2-barrier K-loop.
// EPI 0: C = acc*SCALE + mask[col]*NEG_BIG (QK logits).  EPI 1: C = acc (PV out).
template<int KDIM, int LDA, int LDB, int LDC,
         long long BATCHA, long long BATCHB, long long BATCHC, int EPI>
__global__ void gemm_bt(const ushort* __restrict__ A, const ushort* __restrict__ Bt,
                        float* __restrict__ C, const int* __restrict__ mask) {
  __shared__ __align__(16) ushort As[128 * 32];   // row-major [128][32], 8 KB
  __shared__ __align__(16) ushort Bs[128 * 32];

  int tid  = threadIdx.x;
  int lane = tid & 63;
  int wave = tid >> 6;
  int bn = blockIdx.x, bm = blockIdx.y, b = blockIdx.z;
  int l16 = lane & 15, quad = lane >> 4;
  int wm = (wave & 1) * 64, wn = (wave >> 1) * 64;

  const ushort* Ab = A  + (size_t)b * BATCHA + (size_t)(bm * 128) * LDA;
  const ushort* Bb = Bt + (size_t)b * BATCHB + (size_t)(bn * 128) * LDB;

  f32x4 acc[4][4];
#pragma unroll
  for (int i = 0; i < 4; ++i)
#pragma unroll
    for (int j = 0; j < 4; ++j) acc[i][j] = (f32x4){0.f, 0.f, 0.f, 0.f};

  for (int kc = 0; kc < KDIM / 32; ++kc) {
    __syncthreads();   // all waves done reading previous tile's frags
    // stage A and B tiles: 512 16B-chunks each; chunk c -> row c>>2, slot c&3;
    // LDS byte offset = c*16 (lane-contiguous per global_load_lds constraint).
#pragma unroll
    for (int h = 0; h < 2; ++h) {
      int c = tid + h * 256;
      const ushort* ga = Ab + (size_t)(c >> 2) * LDA + kc * 32 + (c & 3) * 8;
      const ushort* gb = Bb + (size_t)(c >> 2) * LDB + kc * 32 + (c & 3) * 8;
      load16_to_lds(ga, As + c * 8);
      load16_to_lds(gb, Bs + c * 8);
    }
    __syncthreads();   // compiler drains vmcnt(0) here

    short8 af[4], bf[4];
#pragma unroll
    for (int mt = 0; mt < 4; ++mt)
      af[mt] = *(const short8*)(As + (wm + mt * 16 + l16) * 32 + quad * 8);
#pragma unroll
    for (int nt = 0; nt < 4; ++nt)
      bf[nt] = *(const short8*)(Bs + (wn + nt * 16 + l16) * 32 + quad * 8);
#pragma unroll
    for (int mt = 0; mt < 4; ++mt)
#pragma unroll
      for (int nt = 0; nt < 4; ++nt)
        acc[mt][nt] = __builtin_amdgcn_mfma_f32_16x16x32_bf16(af[mt], bf[nt], acc[mt][nt], 0, 0, 0);
  }

  // epilogue. C layout: col = lane&15, row = quad*4 + r
  float* Cb = C + (size_t)b * BATCHC + (size_t)(bm * 128) * LDC + bn * 128;
#pragma unroll
  for (int nt = 0; nt < 4; ++nt) {
    int col = wn + nt * 16 + l16;
    float madd = 0.f;
    if (EPI == 0) madd = mask[b * S_ + bn * 128 + col] ? NEG_BIG : 0.f;
#pragma unroll
    for (int mt = 0; mt < 4; ++mt)
#pragma unroll
      for (int r = 0; r < 4; ++r) {
        int row = wm + mt * 16 + quad * 4 + r;
        float v = acc[mt][nt][r];
        if (EPI == 0) v = v * SCALE + madd;
        Cb[(size_t)row * LDC + col] = v;
      }
  }
}

// ---------------- row softmax: S fp32 [b][q][2048] -> P bf16 normalized ------
__global__ void softmax_rows(const float* __restrict__ S, ushort* __restrict__ P) {
  int q = blockIdx.x, b = blockIdx.y;
  int tid = threadIdx.x, wave = tid >> 6, lane = tid & 63;
  const float* row = S + ((size_t)b * S_ + q) * S_;

  float4 x0 = *(const float4*)(row + tid * 8);
  float4 x1 = *(const float4*)(row + tid * 8 + 4);
  float x[8] = {x0.x, x0.y, x0.z, x0.w, x1.x, x1.y, x1.z, x1.w};

  float m = x[0];
#pragma unroll
  for (int i = 1; i < 8; ++i) m = fmaxf(m, x[i]);
  for (int off = 1; off <= 32; off <<= 1) m = fmaxf(m, __shfl_xor(m, off));
  __shared__ float redm[4], reds[4];
  if (lane == 0) redm[wave] = m;
  __syncthreads();
  m = fmaxf(fmaxf(redm[0], redm[1]), fmaxf(redm[2], redm[3]));

  float e[8], s = 0.f;
#pragma unroll
  for (int i = 0; i < 8; ++i) { e[i] = __expf(x[i] - m); s += e[i]; }
  for (int off = 1; off <= 32; off <<= 1) s += __shfl_xor(s, off);
  if (lane == 0) reds[wave] = s;
  __syncthreads();
  s = reds[0] + reds[1] + reds[2] + reds[3];
  float rinv = 1.0f / s;

  uint4 w;
  w.x = (uint)f2bf(e[0] * rinv) | ((uint)f2bf(e[1] * rinv) << 16);
  w.y = (uint)f2bf(e[2] * rinv) | ((uint)f2bf(e[3] * rinv) << 16);
  w.z = (uint)f2bf(e[4] * rinv) | ((uint)f2bf(e[5] * rinv) << 16);
  w.w = (uint)f2bf(e[6] * rinv) | ((uint)f2bf(e[7] * rinv) << 16);
  *(uint4*)(P + ((size_t)b * S_ + q) * S_ + tid * 8) = w;
}

extern "C" void kernel_launch(void* const* d_in, const int* in_sizes, int n_in,
                              void* d_out, int out_size, void* d_ws, size_t ws_size,
                              hipStream_t stream) {
  const float* Q   = (const float*)d_in[0];
  const float* K   = (const float*)d_in[1];
  const float* V   = (const float*)d_in[2];
  const int*  mask = (const int*)d_in[3];
  float* Out = (float*)d_out;

  // ws layout: Qb(16.78M) Kb(16.78M) Vt(16.78M) S(67.1M fp32) = 117.4 MB.
  // P (bf16, 33.55M) aliases Qb+Kb (both dead after the QK GEMM).
  const size_t E = (size_t)B_ * S_ * D_;   // 8.4M elems
  ushort* Qb = (ushort*)d_ws;
  ushort* Kb = Qb + E;
  ushort* Vt = Kb + E;
  float*  Sb = (float*)(Vt + E);
  ushort* P  = Qb;

  convert_bf16<<<4096, 256, 0, stream>>>(Q, Qb);
  convert_bf16<<<4096, 256, 0, stream>>>(K, Kb);
  transpose_v<<<dim3(32, 16, 4), 256, 0, stream>>>(V, Vt);

  // S[b][q][k] = SCALE * sum_d Qb[q][d] Kb[k][d] + mask[k]*NEG_BIG
  gemm_bt<1024, 1024, 1024, 2048,
          (long long)2048 * 1024, (long long)2048 * 1024, (long long)2048 * 2048, 0>
      <<<dim3(16, 16, 4), 256, 0, stream>>>(Qb, Kb, Sb, mask);

  softmax_rows<<<dim3(2048, 4), 256, 0, stream>>>(Sb, P);

  // Out[b][q][d] = sum_k P[q][k] Vt[d][k]
  gemm_bt<2048, 2048, 2048, 1024,
          (long long)2048 * 2048, (long long)1024 * 2048, (long long)2048 * 1024, 1>
      <<<dim3(8, 16, 4), 256, 0, stream>>>(P, Vt, Out, nullptr);
}

// Round 5
// 244.569 us; speedup vs baseline: 2.3995x; 1.0725x over previous
//
#include <hip/hip_runtime.h>
#include <hip/hip_bf16.h>
#include <cstdint>

#define B_    4
#define S_    2048
#define D_    1024
#define SCALE 0.03125f     // 1/sqrt(1024)
#define NEG_BIG -1e9f

typedef __attribute__((ext_vector_type(8))) short short8;   // 8 bf16 (4 VGPRs)
typedef __attribute__((ext_vector_type(4))) float f32x4;    // MFMA C/D frag

__device__ __forceinline__ ushort f2bf(float f) {
  uint32_t u = __float_as_uint(f);
  u += 0x7fffu + ((u >> 16) & 1u);   // round-to-nearest-even
  return (ushort)(u >> 16);
}

__device__ __forceinline__ void load16_to_lds(const void* g, void* l) {
  __builtin_amdgcn_global_load_lds(
      (const __attribute__((address_space(1))) uint32_t*)g,
      (__attribute__((address_space(3))) uint32_t*)l, 16, 0, 0);
}

// ---------------- fused prep: convert Q, convert K, transpose+convert V -------
// 1D grid 10240 blocks x 256: [0,4096) Q convert, [4096,8192) K convert,
// [8192,10240) V transpose (64x64 tiles).
__global__ void prep(const float* __restrict__ Q, const float* __restrict__ K,
                     const float* __restrict__ V, ushort* __restrict__ Qb,
                     ushort* __restrict__ Kb, ushort* __restrict__ Vt) {
  __shared__ ushort tile[64][68];
  int id = blockIdx.x;
  if (id < 8192) {
    const float* X = (id < 4096) ? Q : K;
    ushort* Xb     = (id < 4096) ? Qb : Kb;
    int cid = id & 4095;
    size_t i = ((size_t)cid * 256 + threadIdx.x) * 8;
    float4 a = *(const float4*)(X + i);
    float4 c = *(const float4*)(X + i + 4);
    uint4 w;
    w.x = (uint)f2bf(a.x) | ((uint)f2bf(a.y) << 16);
    w.y = (uint)f2bf(a.z) | ((uint)f2bf(a.w) << 16);
    w.z = (uint)f2bf(c.x) | ((uint)f2bf(c.y) << 16);
    w.w = (uint)f2bf(c.z) | ((uint)f2bf(c.w) << 16);
    *(uint4*)(Xb + i) = w;
    return;
  }
  int t = id - 8192;                 // 0..2047
  int s0 = (t & 31) * 64, d0 = ((t >> 5) & 15) * 64, b = t >> 9;
  int tx = threadIdx.x & 15, ty = threadIdx.x >> 4;
  const float* src = V + ((size_t)b * S_ + s0) * D_ + d0;
  for (int i = 0; i < 4; ++i) {
    int row = ty + i * 16;
    float4 a = *(const float4*)(src + (size_t)row * D_ + tx * 4);
    ushort4 w;
    w.x = f2bf(a.x); w.y = f2bf(a.y); w.z = f2bf(a.z); w.w = f2bf(a.w);
    *(ushort4*)&tile[row][tx * 4] = w;
  }
  __syncthreads();
  ushort* dst = Vt + ((size_t)b * D_ + d0) * S_ + s0;
  for (int i = 0; i < 4; ++i) {
    int drow = ty + i * 16;
    ushort4 w;
    w.x = tile[tx * 4 + 0][drow];
    w.y = tile[tx * 4 + 1][drow];
    w.z = tile[tx * 4 + 2][drow];
    w.w = tile[tx * 4 + 3][drow];
    *(ushort4*)(dst + (size_t)drow * S_ + tx * 4) = w;
  }
}

// ---------------- m97-style GEMM: C = A * Bt^T, XCD-aware tile assignment ----
// 128x128 tile, 256 threads (4 waves, 64x64 each), BK=32, global_load_lds.
// Block decode (blockIdx.x & 7 = XCD on MI355X): each XCD gets one batch-half
// so its L2 working set is ~A(4.2MB per batch)+B(2.1MB half) with snake order.
// EPI 0: QK logits, grid 1024: xcd -> (batch, bn-half); idx: bm-major, bn snake.
// EPI 1: PV,        grid 512:  xcd -> (batch, bm-half); idx: bm-major, bn snake.
template<int KDIM, int LDA, int LDB, int LDC,
         long long BATCHA, long long BATCHB, long long BATCHC, int EPI>
__global__ void gemm_bt(const ushort* __restrict__ A, const ushort* __restrict__ Bt,
                        float* __restrict__ C, const int* __restrict__ mask) {
  __shared__ __align__(16) ushort As[128 * 32];   // [128][32], 8 KB
  __shared__ __align__(16) ushort Bs[128 * 32];

  int linear = blockIdx.x;
  int xcd = linear & 7, idx = linear >> 3;
  int b = xcd >> 1, half = xcd & 1;
  int bm, bn;
  if (EPI == 0) {            // idx 0..127: bm = idx>>3 (0..15), bn in half*8+snake
    bm = idx >> 3;
    int s = idx & 7;
    bn = half * 8 + ((bm & 1) ? 7 - s : s);
  } else {                   // idx 0..63: bm = half*8 + idx>>3, bn snake 0..7
    int bmh = idx >> 3;
    bm = half * 8 + bmh;
    int s = idx & 7;
    bn = (bmh & 1) ? 7 - s : s;
  }

  int tid  = threadIdx.x;
  int lane = tid & 63;
  int wave = tid >> 6;
  int l16 = lane & 15, quad = lane >> 4;
  int wm = (wave & 1) * 64, wn = (wave >> 1) * 64;

  const ushort* Ab = A  + (size_t)b * BATCHA + (size_t)(bm * 128) * LDA;
  const ushort* Bb = Bt + (size_t)b * BATCHB + (size_t)(bn * 128) * LDB;

  f32x4 acc[4][4];
#pragma unroll
  for (int i = 0; i < 4; ++i)
#pragma unroll
    for (int j = 0; j < 4; ++j) acc[i][j] = (f32x4){0.f, 0.f, 0.f, 0.f};

  for (int kc = 0; kc < KDIM / 32; ++kc) {
    __syncthreads();
#pragma unroll
    for (int h = 0; h < 2; ++h) {
      int c = tid + h * 256;
      const ushort* ga = Ab + (size_t)(c >> 2) * LDA + kc * 32 + (c & 3) * 8;
      const ushort* gb = Bb + (size_t)(c >> 2) * LDB + kc * 32 + (c & 3) * 8;
      load16_to_lds(ga, As + c * 8);
      load16_to_lds(gb, Bs + c * 8);
    }
    __syncthreads();

    short8 af[4], bf[4];
#pragma unroll
    for (int mt = 0; mt < 4; ++mt)
      af[mt] = *(const short8*)(As + (wm + mt * 16 + l16) * 32 + quad * 8);
#pragma unroll
    for (int nt = 0; nt < 4; ++nt)
      bf[nt] = *(const short8*)(Bs + (wn + nt * 16 + l16) * 32 + quad * 8);
#pragma unroll
    for (int mt = 0; mt < 4; ++mt)
#pragma unroll
      for (int nt = 0; nt < 4; ++nt)
        acc[mt][nt] = __builtin_amdgcn_mfma_f32_16x16x32_bf16(af[mt], bf[nt], acc[mt][nt], 0, 0, 0);
  }

  // epilogue. C layout: col = lane&15, row = quad*4 + r
  float* Cb = C + (size_t)b * BATCHC + (size_t)(bm * 128) * LDC + bn * 128;
#pragma unroll
  for (int nt = 0; nt < 4; ++nt) {
    int col = wn + nt * 16 + l16;
    float madd = 0.f;
    if (EPI == 0) madd = mask[b * S_ + bn * 128 + col] ? NEG_BIG : 0.f;
#pragma unroll
    for (int mt = 0; mt < 4; ++mt)
#pragma unroll
      for (int r = 0; r < 4; ++r) {
        int row = wm + mt * 16 + quad * 4 + r;
        float v = acc[mt][nt][r];
        if (EPI == 0) v = v * SCALE + madd;
        Cb[(size_t)row * LDC + col] = v;
      }
  }
}

// ---------------- row softmax: one wave per row, no LDS, no barriers --------
// grid 2048 x 256 threads = 4 rows/block. Lane owns 32 elems (8 float4 strided).
__global__ void softmax_rows(const float* __restrict__ S, ushort* __restrict__ P) {
  int row = blockIdx.x * 4 + (threadIdx.x >> 6);   // 0..8191 = b*2048+q
  int lane = threadIdx.x & 63;
  const float* src = S + (size_t)row * S_;

  float x[32];
#pragma unroll
  for (int j = 0; j < 8; ++j) {
    float4 v = *(const float4*)(src + lane * 4 + j * 256);
    x[j * 4 + 0] = v.x; x[j * 4 + 1] = v.y; x[j * 4 + 2] = v.z; x[j * 4 + 3] = v.w;
  }
  float m = x[0];
#pragma unroll
  for (int i = 1; i < 32; ++i) m = fmaxf(m, x[i]);
  for (int off = 1; off < 64; off <<= 1) m = fmaxf(m, __shfl_xor(m, off));

  float e[32], s = 0.f;
#pragma unroll
  for (int i = 0; i < 32; ++i) { e[i] = __expf(x[i] - m); s += e[i]; }
  for (int off = 1; off < 64; off <<= 1) s += __shfl_xor(s, off);
  float rinv = 1.0f / s;

  ushort* dst = P + (size_t)row * S_;
#pragma unroll
  for (int j = 0; j < 8; ++j) {
    ushort4 w;
    w.x = f2bf(e[j * 4 + 0] * rinv);
    w.y = f2bf(e[j * 4 + 1] * rinv);
    w.z = f2bf(e[j * 4 + 2] * rinv);
    w.w = f2bf(e[j * 4 + 3] * rinv);
    *(ushort4*)(dst + lane * 4 + j * 256) = w;
  }
}

extern "C" void kernel_launch(void* const* d_in, const int* in_sizes, int n_in,
                              void* d_out, int out_size, void* d_ws, size_t ws_size,
                              hipStream_t stream) {
  const float* Q   = (const float*)d_in[0];
  const float* K   = (const float*)d_in[1];
  const float* V   = (const float*)d_in[2];
  const int*  mask = (const int*)d_in[3];
  float* Out = (float*)d_out;

  // ws: Qb(16.78M) Kb(16.78M) Vt(16.78M) S(67.1M fp32) = 117.4 MB.
  // P (bf16, 33.55M) aliases Qb+Kb (dead after QK GEMM).
  const size_t E = (size_t)B_ * S_ * D_;
  ushort* Qb = (ushort*)d_ws;
  ushort* Kb = Qb + E;
  ushort* Vt = Kb + E;
  float*  Sb = (float*)(Vt + E);
  ushort* P  = Qb;

  prep<<<10240, 256, 0, stream>>>(Q, K, V, Qb, Kb, Vt);

  // S[b][q][k] = SCALE * sum_d Qb[q][d] Kb[k][d] + mask[k]*NEG_BIG
  gemm_bt<1024, 1024, 1024, 2048,
          (long long)2048 * 1024, (long long)2048 * 1024, (long long)2048 * 2048, 0>
      <<<1024, 256, 0, stream>>>(Qb, Kb, Sb, mask);

  softmax_rows<<<2048, 256, 0, stream>>>(Sb, P);

  // Out[b][q][d] = sum_k P[q][k] Vt[d][k]
  gemm_bt<2048, 2048, 2048, 1024,
          (long long)2048 * 2048, (long long)1024 * 2048, (long long)2048 * 1024, 1>
      <<<512, 256, 0, stream>>>(P, Vt, Out, nullptr);
}

// Round 6
// 236.209 us; speedup vs baseline: 2.4844x; 1.0354x over previous
//
#include <hip/hip_runtime.h>
#include <hip/hip_bf16.h>
#include <cstdint>

#define B_    4
#define S_    2048
#define D_    1024
#define SCALE 0.03125f     // 1/sqrt(1024)
#define NEG_BIG -1e9f

typedef __attribute__((ext_vector_type(8))) short short8;   // 8 bf16 (4 VGPRs)
typedef __attribute__((ext_vector_type(4))) float f32x4;    // MFMA C/D frag

__device__ __forceinline__ ushort f2bf(float f) {
  uint32_t u = __float_as_uint(f);
  u += 0x7fffu + ((u >> 16) & 1u);   // round-to-nearest-even
  return (ushort)(u >> 16);
}

__device__ __forceinline__ float bf2f(ushort h) {
  return __uint_as_float((uint32_t)h << 16);
}

__device__ __forceinline__ void load16_to_lds(const void* g, void* l) {
  __builtin_amdgcn_global_load_lds(
      (const __attribute__((address_space(1))) uint32_t*)g,
      (__attribute__((address_space(3))) uint32_t*)l, 16, 0, 0);
}

// ---------------- fused prep: convert Q, convert K, transpose+convert V -------
__global__ void prep(const float* __restrict__ Q, const float* __restrict__ K,
                     const float* __restrict__ V, ushort* __restrict__ Qb,
                     ushort* __restrict__ Kb, ushort* __restrict__ Vt) {
  __shared__ ushort tile[64][68];
  int id = blockIdx.x;
  if (id < 8192) {
    const float* X = (id < 4096) ? Q : K;
    ushort* Xb     = (id < 4096) ? Qb : Kb;
    int cid = id & 4095;
    size_t i = ((size_t)cid * 256 + threadIdx.x) * 8;
    float4 a = *(const float4*)(X + i);
    float4 c = *(const float4*)(X + i + 4);
    uint4 w;
    w.x = (uint)f2bf(a.x) | ((uint)f2bf(a.y) << 16);
    w.y = (uint)f2bf(a.z) | ((uint)f2bf(a.w) << 16);
    w.z = (uint)f2bf(c.x) | ((uint)f2bf(c.y) << 16);
    w.w = (uint)f2bf(c.z) | ((uint)f2bf(c.w) << 16);
    *(uint4*)(Xb + i) = w;
    return;
  }
  int t = id - 8192;                 // 0..2047
  int s0 = (t & 31) * 64, d0 = ((t >> 5) & 15) * 64, b = t >> 9;
  int tx = threadIdx.x & 15, ty = threadIdx.x >> 4;
  const float* src = V + ((size_t)b * S_ + s0) * D_ + d0;
  for (int i = 0; i < 4; ++i) {
    int row = ty + i * 16;
    float4 a = *(const float4*)(src + (size_t)row * D_ + tx * 4);
    ushort4 w;
    w.x = f2bf(a.x); w.y = f2bf(a.y); w.z = f2bf(a.z); w.w = f2bf(a.w);
    *(ushort4*)&tile[row][tx * 4] = w;
  }
  __syncthreads();
  ushort* dst = Vt + ((size_t)b * D_ + d0) * S_ + s0;
  for (int i = 0; i < 4; ++i) {
    int drow = ty + i * 16;
    ushort4 w;
    w.x = tile[tx * 4 + 0][drow];
    w.y = tile[tx * 4 + 1][drow];
    w.z = tile[tx * 4 + 2][drow];
    w.w = tile[tx * 4 + 3][drow];
    *(ushort4*)(dst + (size_t)drow * S_ + tx * 4) = w;
  }
}

// ---------------- m97-style GEMM: C = A * Bt^T, XCD-aware tile assignment ----
// 128x128 tile, 256 threads (4 waves, 64x64 each), BK=32, global_load_lds.
// blockIdx.x & 7 = XCD; each XCD gets one batch-half (L2-sized working set).
// EPI 0: C bf16 = f2bf(acc*SCALE + mask[col]*NEG_BIG).  EPI 1: C fp32 = acc.
template<int KDIM, int LDA, int LDB, int LDC,
         long long BATCHA, long long BATCHB, long long BATCHC, int EPI, typename OutT>
__global__ void gemm_bt(const ushort* __restrict__ A, const ushort* __restrict__ Bt,
                        OutT* __restrict__ C, const int* __restrict__ mask) {
  __shared__ __align__(16) ushort As[128 * 32];   // [128][32], 8 KB
  __shared__ __align__(16) ushort Bs[128 * 32];

  int linear = blockIdx.x;
  int xcd = linear & 7, idx = linear >> 3;
  int b = xcd >> 1, half = xcd & 1;
  int bm, bn;
  if (EPI == 0) {            // idx 0..127: bm 0..15, bn in half*8 + snake
    bm = idx >> 3;
    int s = idx & 7;
    bn = half * 8 + ((bm & 1) ? 7 - s : s);
  } else {                   // idx 0..63: bm = half*8 + idx>>3, bn snake 0..7
    int bmh = idx >> 3;
    bm = half * 8 + bmh;
    int s = idx & 7;
    bn = (bmh & 1) ? 7 - s : s;
  }

  int tid  = threadIdx.x;
  int lane = tid & 63;
  int wave = tid >> 6;
  int l16 = lane & 15, quad = lane >> 4;
  int wm = (wave & 1) * 64, wn = (wave >> 1) * 64;

  // mask prefetch (QK only): off the epilogue critical path
  float madd[4];
  if (EPI == 0) {
#pragma unroll
    for (int nt = 0; nt < 4; ++nt)
      madd[nt] = mask[b * S_ + bn * 128 + wn + nt * 16 + l16] ? NEG_BIG : 0.f;
  }

  const ushort* Ab = A  + (size_t)b * BATCHA + (size_t)(bm * 128) * LDA;
  const ushort* Bb = Bt + (size_t)b * BATCHB + (size_t)(bn * 128) * LDB;

  f32x4 acc[4][4];
#pragma unroll
  for (int i = 0; i < 4; ++i)
#pragma unroll
    for (int j = 0; j < 4; ++j) acc[i][j] = (f32x4){0.f, 0.f, 0.f, 0.f};

  for (int kc = 0; kc < KDIM / 32; ++kc) {
    __syncthreads();
#pragma unroll
    for (int h = 0; h < 2; ++h) {
      int c = tid + h * 256;
      const ushort* ga = Ab + (size_t)(c >> 2) * LDA + kc * 32 + (c & 3) * 8;
      const ushort* gb = Bb + (size_t)(c >> 2) * LDB + kc * 32 + (c & 3) * 8;
      load16_to_lds(ga, As + c * 8);
      load16_to_lds(gb, Bs + c * 8);
    }
    __syncthreads();

    short8 af[4], bf[4];
#pragma unroll
    for (int mt = 0; mt < 4; ++mt)
      af[mt] = *(const short8*)(As + (wm + mt * 16 + l16) * 32 + quad * 8);
#pragma unroll
    for (int nt = 0; nt < 4; ++nt)
      bf[nt] = *(const short8*)(Bs + (wn + nt * 16 + l16) * 32 + quad * 8);
#pragma unroll
    for (int mt = 0; mt < 4; ++mt)
#pragma unroll
      for (int nt = 0; nt < 4; ++nt)
        acc[mt][nt] = __builtin_amdgcn_mfma_f32_16x16x32_bf16(af[mt], bf[nt], acc[mt][nt], 0, 0, 0);
  }

  // epilogue. C layout: col = lane&15, row = quad*4 + r
  OutT* Cb = C + (size_t)b * BATCHC + (size_t)(bm * 128) * LDC + bn * 128;
#pragma unroll
  for (int nt = 0; nt < 4; ++nt) {
    int col = wn + nt * 16 + l16;
#pragma unroll
    for (int mt = 0; mt < 4; ++mt)
#pragma unroll
      for (int r = 0; r < 4; ++r) {
        int row = wm + mt * 16 + quad * 4 + r;
        float v = acc[mt][nt][r];
        if (EPI == 0)
          Cb[(size_t)row * LDC + col] = (OutT)f2bf(v * SCALE + madd[nt]);
        else
          Cb[(size_t)row * LDC + col] = (OutT)v;
      }
  }
}

// ---------------- row softmax: S bf16 -> P bf16, one wave per row ------------
// grid 2048 x 256 = 4 rows/block. Lane owns 32 elems (4 x uint4 = 4x8 bf16).
__global__ void softmax_rows(const ushort* __restrict__ S, ushort* __restrict__ P) {
  int row = blockIdx.x * 4 + (threadIdx.x >> 6);   // 0..8191 = b*2048+q
  int lane = threadIdx.x & 63;
  const ushort* src = S + (size_t)row * S_;

  float x[32];
#pragma unroll
  for (int j = 0; j < 4; ++j) {
    uint4 v = *(const uint4*)(src + lane * 8 + j * 512);
    uint32_t w[4] = {v.x, v.y, v.z, v.w};
#pragma unroll
    for (int t = 0; t < 4; ++t) {
      x[j * 8 + t * 2 + 0] = __uint_as_float(w[t] << 16);
      x[j * 8 + t * 2 + 1] = __uint_as_float(w[t] & 0xffff0000u);
    }
  }
  float m = x[0];
#pragma unroll
  for (int i = 1; i < 32; ++i) m = fmaxf(m, x[i]);
  for (int off = 1; off < 64; off <<= 1) m = fmaxf(m, __shfl_xor(m, off));

  float e[32], s = 0.f;
#pragma unroll
  for (int i = 0; i < 32; ++i) { e[i] = __expf(x[i] - m); s += e[i]; }
  for (int off = 1; off < 64; off <<= 1) s += __shfl_xor(s, off);
  float rinv = 1.0f / s;

  ushort* dst = P + (size_t)row * S_;
#pragma unroll
  for (int j = 0; j < 4; ++j) {
    uint4 w;
    uint32_t* pw = &w.x;
#pragma unroll
    for (int t = 0; t < 4; ++t)
      pw[t] = (uint32_t)f2bf(e[j * 8 + t * 2] * rinv) |
              ((uint32_t)f2bf(e[j * 8 + t * 2 + 1] * rinv) << 16);
    *(uint4*)(dst + lane * 8 + j * 512) = w;
  }
}

extern "C" void kernel_launch(void* const* d_in, const int* in_sizes, int n_in,
                              void* d_out, int out_size, void* d_ws, size_t ws_size,
                              hipStream_t stream) {
  const float* Q   = (const float*)d_in[0];
  const float* K   = (const float*)d_in[1];
  const float* V   = (const float*)d_in[2];
  const int*  mask = (const int*)d_in[3];
  float* Out = (float*)d_out;

  // ws: Qb(16.78M) Kb(16.78M) Vt(16.78M) Sb(bf16, 33.55M) = 83.9 MB.
  // P (bf16, 33.55M) aliases Qb+Kb (dead after QK GEMM).
  const size_t E = (size_t)B_ * S_ * D_;
  ushort* Qb = (ushort*)d_ws;
  ushort* Kb = Qb + E;
  ushort* Vt = Kb + E;
  ushort* Sb = Vt + E;
  ushort* P  = Qb;

  prep<<<10240, 256, 0, stream>>>(Q, K, V, Qb, Kb, Vt);

  // S[b][q][k] = bf16( SCALE * sum_d Qb[q][d] Kb[k][d] + mask[k]*NEG_BIG )
  gemm_bt<1024, 1024, 1024, 2048,
          (long long)2048 * 1024, (long long)2048 * 1024, (long long)2048 * 2048, 0, ushort>
      <<<1024, 256, 0, stream>>>(Qb, Kb, Sb, mask);

  softmax_rows<<<2048, 256, 0, stream>>>(Sb, P);

  // Out[b][q][d] = sum_k P[q][k] Vt[d][k]
  gemm_bt<2048, 2048, 2048, 1024,
          (long long)2048 * 2048, (long long)1024 * 2048, (long long)2048 * 1024, 1, float>
      <<<512, 256, 0, stream>>>(P, Vt, Out, nullptr);
}